// Round 1
// baseline (1053.968 us; speedup 1.0000x reference)
//
#include <hip/hip_runtime.h>

#define N_NODES  100000
#define N_EDGES  1600000
#define N_GRAPHS 256

__device__ __forceinline__ void atomAddF(float* p, float v) {
#if defined(__gfx90a__) || defined(__gfx940__) || defined(__gfx941__) || defined(__gfx942__) || defined(__gfx950__)
    unsafeAtomicAdd(p, v);   // hardware global_atomic_add_f32
#else
    atomicAdd(p, v);
#endif
}

// K1: in-degree via dst (self-loop handled as +1.0 later)
__global__ void k_edge_deg(const int* __restrict__ dst, float* __restrict__ deg, int nE) {
    int e = blockIdx.x * blockDim.x + threadIdx.x;
    if (e < nE) atomAddF(&deg[dst[e]], 1.0f);
}

// K2: dinv = rsqrt(deg+1), t = x*dinv
__global__ void k_node_prep(const float* __restrict__ x, const float* __restrict__ deg,
                            float* __restrict__ dinv, float* __restrict__ t, int nN) {
    int i = blockIdx.x * blockDim.x + threadIdx.x;
    if (i < nN) {
        float dv = rsqrtf(deg[i] + 1.0f);
        dinv[i] = dv;
        t[i] = x[i] * dv;
    }
}

// K3: scalar layer-1 aggregation: agg1[d] += t[s]
__global__ void k_edge_agg1(const int* __restrict__ src, const int* __restrict__ dst,
                            const float* __restrict__ t, float* __restrict__ agg1, int nE) {
    int e = blockIdx.x * blockDim.x + threadIdx.x;
    if (e < nE) atomAddF(&agg1[dst[e]], t[src[e]]);
}

// K4: per node: a = dinv*(agg1+t); h1 = relu(a*W1+b1); g[i][k] = dinv * sum_j h1[j]*W2[j][k]
// thread -> (node i = gtid>>6, channel k = gtid&63)
__global__ void k_node_layer(const float* __restrict__ agg1, const float* __restrict__ t,
                             const float* __restrict__ dinv,
                             const float* __restrict__ W1, const float* __restrict__ b1,
                             const float* __restrict__ W2,
                             float* __restrict__ g, int nN) {
    __shared__ float sW1[32], sb1[32], sW2[32 * 64];
    int tid = threadIdx.x;
    if (tid < 32) { sW1[tid] = W1[tid]; sb1[tid] = b1[tid]; }
    for (int j = tid; j < 32 * 64; j += blockDim.x) sW2[j] = W2[j];
    __syncthreads();
    int gtid = blockIdx.x * blockDim.x + tid;
    int i = gtid >> 6, k = gtid & 63;
    if (i < nN) {
        float dv = dinv[i];
        float a  = dv * (agg1[i] + t[i]);
        float acc = 0.f;
#pragma unroll
        for (int j = 0; j < 32; ++j) {
            float h1 = fmaxf(fmaf(a, sW1[j], sb1[j]), 0.f);
            acc = fmaf(h1, sW2[j * 64 + k], acc);   // 2-way LDS bank alias: free
        }
        g[(size_t)i * 64 + k] = acc * dv;
    }
}

// K5 (hot): layer-2 aggregation: agg2[d][k] += g[s][k]  (102.4M fp32 atomics)
__global__ void k_edge_agg2(const int* __restrict__ src, const int* __restrict__ dst,
                            const float* __restrict__ g, float* __restrict__ agg2, int nE) {
    int gtid = blockIdx.x * blockDim.x + threadIdx.x;
    int e = gtid >> 6, k = gtid & 63;
    if (e < nE) {
        int s = src[e], d = dst[e];          // wave-uniform loads (broadcast)
        atomAddF(&agg2[(size_t)d * 64 + k], g[(size_t)s * 64 + k]);
    }
}

// K6: h2 = relu(dinv*(agg2+g)+b2); y = h2 . Wl ; graph-scatter the scalar
__global__ void k_node_out(const float* __restrict__ agg2, const float* __restrict__ g,
                           const float* __restrict__ dinv, const float* __restrict__ b2,
                           const float* __restrict__ Wl, const int* __restrict__ batch,
                           float* __restrict__ gsum, float* __restrict__ gcnt, int nN) {
    int gtid = blockIdx.x * blockDim.x + threadIdx.x;
    int i = gtid >> 6, k = gtid & 63;      // one wave per node, lane = channel
    if (i >= nN) return;
    float dv = dinv[i];
    size_t o = (size_t)i * 64 + k;
    float v = fmaxf(fmaf(dv, agg2[o] + g[o], b2[k]), 0.f);
    float y = v * Wl[k];
#pragma unroll
    for (int off = 32; off > 0; off >>= 1) y += __shfl_down(y, off, 64);
    if (k == 0) {
        int b = batch[i];
        atomAddF(&gsum[b], y);
        atomAddF(&gcnt[b], 1.0f);
    }
}

// K7: out[g] = gsum/cnt + bl
__global__ void k_final(const float* __restrict__ gsum, const float* __restrict__ gcnt,
                        const float* __restrict__ bl, float* __restrict__ out, int nG) {
    int i = blockIdx.x * blockDim.x + threadIdx.x;
    if (i < nG) out[i] = gsum[i] / fmaxf(gcnt[i], 1.0f) + bl[0];
}

extern "C" void kernel_launch(void* const* d_in, const int* in_sizes, int n_in,
                              void* d_out, int out_size, void* d_ws, size_t ws_size,
                              hipStream_t stream) {
    const float* x   = (const float*)d_in[0];
    const int* eidx  = (const int*)d_in[1];
    const int* batch = (const int*)d_in[2];
    const float* W1  = (const float*)d_in[3];
    const float* b1  = (const float*)d_in[4];
    const float* W2  = (const float*)d_in[5];
    const float* b2  = (const float*)d_in[6];
    const float* Wl  = (const float*)d_in[7];
    const float* bl  = (const float*)d_in[8];
    const int* src = eidx;
    const int* dst = eidx + N_EDGES;

    float* ws = (float*)d_ws;
    size_t off = 0;
    float* agg2 = ws + off; off += (size_t)N_NODES * 64;
    float* agg1 = ws + off; off += N_NODES;
    float* deg  = ws + off; off += N_NODES;
    float* gsum = ws + off; off += N_GRAPHS;
    float* gcnt = ws + off; off += N_GRAPHS;
    size_t zeroFloats = off;                 // everything above must start at 0
    float* dinv = ws + off; off += N_NODES;
    float* t    = ws + off; off += N_NODES;
    float* g    = ws + off; off += (size_t)N_NODES * 64;

    hipMemsetAsync(ws, 0, zeroFloats * sizeof(float), stream);

    k_edge_deg <<<(N_EDGES + 255) / 256, 256, 0, stream>>>(dst, deg, N_EDGES);
    k_node_prep<<<(N_NODES + 255) / 256, 256, 0, stream>>>(x, deg, dinv, t, N_NODES);
    k_edge_agg1<<<(N_EDGES + 255) / 256, 256, 0, stream>>>(src, dst, t, agg1, N_EDGES);
    k_node_layer<<<((size_t)N_NODES * 64 + 255) / 256, 256, 0, stream>>>(
        agg1, t, dinv, W1, b1, W2, g, N_NODES);
    k_edge_agg2<<<((size_t)N_EDGES * 64 + 255) / 256, 256, 0, stream>>>(
        src, dst, g, agg2, N_EDGES);
    k_node_out <<<((size_t)N_NODES * 64 + 255) / 256, 256, 0, stream>>>(
        agg2, g, dinv, b2, Wl, batch, gsum, gcnt, N_NODES);
    k_final    <<<1, 256, 0, stream>>>(gsum, gcnt, bl, (float*)d_out, N_GRAPHS);
}

// Round 2
// 650.206 us; speedup vs baseline: 1.6210x; 1.6210x over previous
//
#include <hip/hip_runtime.h>

#define N_NODES  100000
#define N_EDGES  1600000
#define N_GRAPHS 256

__device__ __forceinline__ void atomAddF(float* p, float v) {
#if defined(__gfx90a__) || defined(__gfx940__) || defined(__gfx941__) || defined(__gfx942__) || defined(__gfx950__)
    unsafeAtomicAdd(p, v);   // hardware global_atomic_add_f32
#else
    atomicAdd(p, v);
#endif
}

// K1: in-degree via dst (self-loop handled as +1.0 later)
__global__ void k_edge_deg(const int* __restrict__ dst, float* __restrict__ deg, int nE) {
    int e = blockIdx.x * blockDim.x + threadIdx.x;
    if (e < nE) atomAddF(&deg[dst[e]], 1.0f);
}

// K2: dinv = rsqrt(deg+1), t = x*dinv
__global__ void k_node_prep(const float* __restrict__ x, const float* __restrict__ deg,
                            float* __restrict__ dinv, float* __restrict__ t, int nN) {
    int i = blockIdx.x * blockDim.x + threadIdx.x;
    if (i < nN) {
        float dv = rsqrtf(deg[i] + 1.0f);
        dinv[i] = dv;
        t[i] = x[i] * dv;
    }
}

// K3: scalar layer-1 aggregation: agg1[d] += t[s]
__global__ void k_edge_agg1(const int* __restrict__ src, const int* __restrict__ dst,
                            const float* __restrict__ t, float* __restrict__ agg1, int nE) {
    int e = blockIdx.x * blockDim.x + threadIdx.x;
    if (e < nE) atomAddF(&agg1[dst[e]], t[src[e]]);
}

// K4: per node: a = dinv*(agg1+t); h1 = relu(a*W1+b1); g[i][k] = dinv * sum_j h1[j]*W2[j][k]
__global__ void k_node_layer(const float* __restrict__ agg1, const float* __restrict__ t,
                             const float* __restrict__ dinv,
                             const float* __restrict__ W1, const float* __restrict__ b1,
                             const float* __restrict__ W2,
                             float* __restrict__ g, int nN) {
    __shared__ float sW1[32], sb1[32], sW2[32 * 64];
    int tid = threadIdx.x;
    if (tid < 32) { sW1[tid] = W1[tid]; sb1[tid] = b1[tid]; }
    for (int j = tid; j < 32 * 64; j += blockDim.x) sW2[j] = W2[j];
    __syncthreads();
    int gtid = blockIdx.x * blockDim.x + tid;
    int i = gtid >> 6, k = gtid & 63;
    if (i < nN) {
        float dv = dinv[i];
        float a  = dv * (agg1[i] + t[i]);
        float acc = 0.f;
#pragma unroll
        for (int j = 0; j < 32; ++j) {
            float h1 = fmaxf(fmaf(a, sW1[j], sb1[j]), 0.f);
            acc = fmaf(h1, sW2[j * 64 + k], acc);
        }
        g[(size_t)i * 64 + k] = acc * dv;
    }
}

// K5 (hot): layer-2 aggregation: agg2[d][k] += g[s][k]  (102.4M fp32 atomics, 6.4M addrs)
__global__ void k_edge_agg2(const int* __restrict__ src, const int* __restrict__ dst,
                            const float* __restrict__ g, float* __restrict__ agg2, int nE) {
    int gtid = blockIdx.x * blockDim.x + threadIdx.x;
    int e = gtid >> 6, k = gtid & 63;
    if (e < nE) {
        int s = src[e], d = dst[e];          // wave-uniform loads (broadcast)
        atomAddF(&agg2[(size_t)d * 64 + k], g[(size_t)s * 64 + k]);
    }
}

// K6: per-node output scalar y[i] = relu(dinv*(agg2+g)+b2) . Wl   (NO atomics)
// 16 lanes per node, float4 per lane -> 64 channels; shuffle-reduce width 16.
__global__ void k_node_y(const float* __restrict__ agg2, const float* __restrict__ g,
                         const float* __restrict__ dinv, const float* __restrict__ b2,
                         const float* __restrict__ Wl, float* __restrict__ y, int nN) {
    int gtid = blockIdx.x * blockDim.x + threadIdx.x;
    int i = gtid >> 4;           // node
    int q = gtid & 15;           // 16B chunk within the 64-float row
    if (i >= nN) return;
    float dv = dinv[i];
    float4 a  = ((const float4*)(agg2 + (size_t)i * 64))[q];
    float4 gg = ((const float4*)(g    + (size_t)i * 64))[q];
    float4 bb = ((const float4*)b2)[q];
    float4 wl = ((const float4*)Wl)[q];
    float s = 0.f;
    s = fmaf(fmaxf(fmaf(dv, a.x + gg.x, bb.x), 0.f), wl.x, s);
    s = fmaf(fmaxf(fmaf(dv, a.y + gg.y, bb.y), 0.f), wl.y, s);
    s = fmaf(fmaxf(fmaf(dv, a.z + gg.z, bb.z), 0.f), wl.z, s);
    s = fmaf(fmaxf(fmaf(dv, a.w + gg.w, bb.w), 0.f), wl.w, s);
#pragma unroll
    for (int off = 8; off > 0; off >>= 1) s += __shfl_down(s, off, 16);
    if (q == 0) y[i] = s;
}

// K7: one block per graph; binary-search sorted batch for [start,end), reduce y.
__global__ void k_pool(const float* __restrict__ y, const int* __restrict__ batch,
                       const float* __restrict__ bl, float* __restrict__ out, int nN) {
    int gid = blockIdx.x;
    // lower_bound(batch, gid) and lower_bound(batch, gid+1) — wave-uniform search
    int lo = 0, hi = nN;
    while (lo < hi) { int m = (lo + hi) >> 1; if (batch[m] < gid) lo = m + 1; else hi = m; }
    int start = lo;
    hi = nN;
    while (lo < hi) { int m = (lo + hi) >> 1; if (batch[m] < gid + 1) lo = m + 1; else hi = m; }
    int end = lo;

    float acc = 0.f;
    for (int i = start + threadIdx.x; i < end; i += blockDim.x) acc += y[i];
#pragma unroll
    for (int off = 32; off > 0; off >>= 1) acc += __shfl_down(acc, off, 64);
    __shared__ float ws_[4];
    int lane = threadIdx.x & 63, wv = threadIdx.x >> 6;
    if (lane == 0) ws_[wv] = acc;
    __syncthreads();
    if (threadIdx.x == 0) {
        float s = ws_[0] + ws_[1] + ws_[2] + ws_[3];
        out[gid] = s / fmaxf((float)(end - start), 1.0f) + bl[0];
    }
}

extern "C" void kernel_launch(void* const* d_in, const int* in_sizes, int n_in,
                              void* d_out, int out_size, void* d_ws, size_t ws_size,
                              hipStream_t stream) {
    const float* x   = (const float*)d_in[0];
    const int* eidx  = (const int*)d_in[1];
    const int* batch = (const int*)d_in[2];
    const float* W1  = (const float*)d_in[3];
    const float* b1  = (const float*)d_in[4];
    const float* W2  = (const float*)d_in[5];
    const float* b2  = (const float*)d_in[6];
    const float* Wl  = (const float*)d_in[7];
    const float* bl  = (const float*)d_in[8];
    const int* src = eidx;
    const int* dst = eidx + N_EDGES;

    float* ws = (float*)d_ws;
    size_t off = 0;
    float* agg2 = ws + off; off += (size_t)N_NODES * 64;
    float* agg1 = ws + off; off += N_NODES;
    float* deg  = ws + off; off += N_NODES;
    size_t zeroFloats = off;                 // everything above must start at 0
    float* dinv = ws + off; off += N_NODES;
    float* t    = ws + off; off += N_NODES;
    float* g    = ws + off; off += (size_t)N_NODES * 64;
    float* y    = ws + off; off += N_NODES;

    hipMemsetAsync(ws, 0, zeroFloats * sizeof(float), stream);

    k_edge_deg <<<(N_EDGES + 255) / 256, 256, 0, stream>>>(dst, deg, N_EDGES);
    k_node_prep<<<(N_NODES + 255) / 256, 256, 0, stream>>>(x, deg, dinv, t, N_NODES);
    k_edge_agg1<<<(N_EDGES + 255) / 256, 256, 0, stream>>>(src, dst, t, agg1, N_EDGES);
    k_node_layer<<<((size_t)N_NODES * 64 + 255) / 256, 256, 0, stream>>>(
        agg1, t, dinv, W1, b1, W2, g, N_NODES);
    k_edge_agg2<<<((size_t)N_EDGES * 64 + 255) / 256, 256, 0, stream>>>(
        src, dst, g, agg2, N_EDGES);
    k_node_y   <<<((size_t)N_NODES * 16 + 255) / 256, 256, 0, stream>>>(
        agg2, g, dinv, b2, Wl, y, N_NODES);
    k_pool     <<<N_GRAPHS, 256, 0, stream>>>(y, batch, bl, (float*)d_out, N_NODES);
}

// Round 3
// 422.304 us; speedup vs baseline: 2.4958x; 1.5397x over previous
//
#include <hip/hip_runtime.h>

#define N_NODES  100000
#define N_EDGES  1600000
#define N_GRAPHS 256

__device__ __forceinline__ void atomAddF(float* p, float v) {
#if defined(__gfx90a__) || defined(__gfx940__) || defined(__gfx941__) || defined(__gfx942__) || defined(__gfx950__)
    unsafeAtomicAdd(p, v);
#else
    atomicAdd(p, v);
#endif
}

// ---- CSR build ----------------------------------------------------------

// K1: int in-degree histogram over dst
__global__ void k_hist(const int* __restrict__ dst, int* __restrict__ deg, int nE) {
    int e = blockIdx.x * blockDim.x + threadIdx.x;
    if (e < nE) atomicAdd(&deg[dst[e]], 1);
}

// Scan pass 1: per-block (1024 elems) sums
__global__ void k_scan1(const int* __restrict__ deg, int* __restrict__ bsum, int n) {
    __shared__ int sm[256];
    int base = blockIdx.x * 1024 + threadIdx.x * 4;
    int s = 0;
#pragma unroll
    for (int u = 0; u < 4; ++u) { int idx = base + u; if (idx < n) s += deg[idx]; }
    sm[threadIdx.x] = s; __syncthreads();
    for (int st = 128; st > 0; st >>= 1) {
        if (threadIdx.x < st) sm[threadIdx.x] += sm[threadIdx.x + st];
        __syncthreads();
    }
    if (threadIdx.x == 0) bsum[blockIdx.x] = sm[0];
}

// Scan pass 2: single block exclusive-scans the (<=128) block sums
__global__ void k_scan2(int* __restrict__ bsum, int nb) {
    __shared__ int sm[128];
    int v = (threadIdx.x < nb) ? bsum[threadIdx.x] : 0;
    sm[threadIdx.x] = v; __syncthreads();
    for (int st = 1; st < 128; st <<= 1) {
        int t_ = 0;
        if ((int)threadIdx.x >= st) t_ = sm[threadIdx.x - st];
        __syncthreads();
        sm[threadIdx.x] += t_;
        __syncthreads();
    }
    if ((int)threadIdx.x < nb) bsum[threadIdx.x] = sm[threadIdx.x] - v;  // exclusive
}

// Scan pass 3: write exclusive rowptr (and cursor copy)
__global__ void k_scan3(const int* __restrict__ deg, const int* __restrict__ bsum,
                        int* __restrict__ rowptr, int* __restrict__ cursor, int n) {
    __shared__ int sm[256];
    int base = blockIdx.x * 1024 + threadIdx.x * 4;
    int v[4]; int s = 0;
#pragma unroll
    for (int u = 0; u < 4; ++u) { int idx = base + u; v[u] = (idx < n) ? deg[idx] : 0; s += v[u]; }
    sm[threadIdx.x] = s; __syncthreads();
    for (int st = 1; st < 256; st <<= 1) {
        int t_ = 0;
        if ((int)threadIdx.x >= st) t_ = sm[threadIdx.x - st];
        __syncthreads();
        sm[threadIdx.x] += t_;
        __syncthreads();
    }
    int off = bsum[blockIdx.x] + sm[threadIdx.x] - s;   // exclusive offset
#pragma unroll
    for (int u = 0; u < 4; ++u) {
        int idx = base + u;
        if (idx < n) { rowptr[idx] = off; cursor[idx] = off; off += v[u]; }
    }
    if (blockIdx.x == 0 && threadIdx.x == 0) rowptr[n] = N_EDGES;
}

// K2: fill CSR (src grouped by dst)
__global__ void k_csr_fill(const int* __restrict__ src, const int* __restrict__ dst,
                           int* __restrict__ cursor, int* __restrict__ csr, int nE) {
    int e = blockIdx.x * blockDim.x + threadIdx.x;
    if (e < nE) {
        int d = dst[e];
        int pos = atomicAdd(&cursor[d], 1);
        csr[pos] = src[e];
    }
}

// ---- Node compute -------------------------------------------------------

// K3: dinv = rsqrt(deg_in+1), t = x*dinv
__global__ void k_node_prep(const float* __restrict__ x, const int* __restrict__ deg,
                            float* __restrict__ dinv, float* __restrict__ t, int nN) {
    int i = blockIdx.x * blockDim.x + threadIdx.x;
    if (i < nN) {
        float dv = rsqrtf((float)deg[i] + 1.0f);
        dinv[i] = dv;
        t[i] = x[i] * dv;
    }
}

// K4: wave per node. Gather agg1 = sum t[src] (lane-parallel + butterfly),
// then layer1 MLP + W2 projection: g[i][k] = dinv * sum_j relu(a*W1+b1)[j] * W2[j][k]
__global__ void k_fused1(const int* __restrict__ rowptr, const int* __restrict__ csr,
                         const float* __restrict__ t, const float* __restrict__ dinv,
                         const float* __restrict__ W1, const float* __restrict__ b1,
                         const float* __restrict__ W2, float* __restrict__ g, int nN) {
    __shared__ float sW1[32], sb1[32], sW2[32 * 64];
    int tid = threadIdx.x;
    if (tid < 32) { sW1[tid] = W1[tid]; sb1[tid] = b1[tid]; }
    for (int j = tid; j < 32 * 64; j += 256) sW2[j] = W2[j];
    __syncthreads();
    int i    = (blockIdx.x * 256 + tid) >> 6;
    int lane = tid & 63;
    if (i >= nN) return;
    int rs = rowptr[i], re = rowptr[i + 1];
    float a1 = 0.f;
    for (int j = rs + lane; j < re; j += 64) a1 += t[csr[j]];
#pragma unroll
    for (int st = 32; st > 0; st >>= 1) a1 += __shfl_xor(a1, st, 64);
    float dv = dinv[i];
    float a  = dv * (a1 + t[i]);
    float acc = 0.f;
#pragma unroll
    for (int j = 0; j < 32; ++j) {
        float h1 = fmaxf(fmaf(a, sW1[j], sb1[j]), 0.f);
        acc = fmaf(h1, sW2[j * 64 + lane], acc);
    }
    g[(size_t)i * 64 + lane] = acc * dv;
}

// K5 (hot): wave per node, lane = channel. Gather sum of g[s][:] over in-edges
// (one coalesced 256B read per edge), fused layer-2 epilogue + y = h2 . Wl.
__global__ void k_fused2(const int* __restrict__ rowptr, const int* __restrict__ csr,
                         const float* __restrict__ g, const float* __restrict__ dinv,
                         const float* __restrict__ b2, const float* __restrict__ Wl,
                         float* __restrict__ y, int nN) {
    int tid  = threadIdx.x;
    int i    = (blockIdx.x * 256 + tid) >> 6;
    int lane = tid & 63;
    if (i >= nN) return;
    int rs = rowptr[i], re = rowptr[i + 1];
    float acc0 = 0.f, acc1 = 0.f;
    int j = rs;
    for (; j + 1 < re; j += 2) {               // 2-wide unroll for outstanding loads
        int s0 = csr[j], s1 = csr[j + 1];
        acc0 += g[(size_t)s0 * 64 + lane];
        acc1 += g[(size_t)s1 * 64 + lane];
    }
    if (j < re) acc0 += g[(size_t)csr[j] * 64 + lane];
    float acc = acc0 + acc1 + g[(size_t)i * 64 + lane];   // self-loop
    float h2 = fmaxf(fmaf(dinv[i], acc, b2[lane]), 0.f);
    float yv = h2 * Wl[lane];
#pragma unroll
    for (int st = 32; st > 0; st >>= 1) yv += __shfl_xor(yv, st, 64);
    if (lane == 0) y[i] = yv;
}

// K6: one block per graph; binary-search sorted batch for [start,end), reduce y.
__global__ void k_pool(const float* __restrict__ y, const int* __restrict__ batch,
                       const float* __restrict__ bl, float* __restrict__ out, int nN) {
    int gid = blockIdx.x;
    int lo = 0, hi = nN;
    while (lo < hi) { int m = (lo + hi) >> 1; if (batch[m] < gid) lo = m + 1; else hi = m; }
    int start = lo;
    hi = nN;
    while (lo < hi) { int m = (lo + hi) >> 1; if (batch[m] < gid + 1) lo = m + 1; else hi = m; }
    int end = lo;

    float acc = 0.f;
    for (int i = start + threadIdx.x; i < end; i += blockDim.x) acc += y[i];
#pragma unroll
    for (int off = 32; off > 0; off >>= 1) acc += __shfl_down(acc, off, 64);
    __shared__ float ws_[4];
    int lane = threadIdx.x & 63, wv = threadIdx.x >> 6;
    if (lane == 0) ws_[wv] = acc;
    __syncthreads();
    if (threadIdx.x == 0) {
        float s = ws_[0] + ws_[1] + ws_[2] + ws_[3];
        out[gid] = s / fmaxf((float)(end - start), 1.0f) + bl[0];
    }
}

extern "C" void kernel_launch(void* const* d_in, const int* in_sizes, int n_in,
                              void* d_out, int out_size, void* d_ws, size_t ws_size,
                              hipStream_t stream) {
    const float* x   = (const float*)d_in[0];
    const int* eidx  = (const int*)d_in[1];
    const int* batch = (const int*)d_in[2];
    const float* W1  = (const float*)d_in[3];
    const float* b1  = (const float*)d_in[4];
    const float* W2  = (const float*)d_in[5];
    const float* b2  = (const float*)d_in[6];
    const float* Wl  = (const float*)d_in[7];
    const float* bl  = (const float*)d_in[8];
    const int* src = eidx;
    const int* dst = eidx + N_EDGES;

    const int SCAN_NB = (N_NODES + 1023) / 1024;   // 98 blocks

    char* ws = (char*)d_ws;
    size_t off = 0;
    auto alloc = [&](size_t elems) { void* p = ws + off; off += elems * 4; return p; };
    int*   deg    = (int*)alloc(N_NODES);          // must start at 0
    int*   bsum   = (int*)alloc(128);
    int*   rowptr = (int*)alloc(N_NODES + 1);
    int*   cursor = (int*)alloc(N_NODES);
    int*   csr    = (int*)alloc(N_EDGES);
    float* dinv   = (float*)alloc(N_NODES);
    float* t      = (float*)alloc(N_NODES);
    float* g      = (float*)alloc((size_t)N_NODES * 64);
    float* y      = (float*)alloc(N_NODES);

    hipMemsetAsync(deg, 0, N_NODES * sizeof(int), stream);

    k_hist    <<<(N_EDGES + 255) / 256, 256, 0, stream>>>(dst, deg, N_EDGES);
    k_scan1   <<<SCAN_NB, 256, 0, stream>>>(deg, bsum, N_NODES);
    k_scan2   <<<1, 128, 0, stream>>>(bsum, SCAN_NB);
    k_scan3   <<<SCAN_NB, 256, 0, stream>>>(deg, bsum, rowptr, cursor, N_NODES);
    k_csr_fill<<<(N_EDGES + 255) / 256, 256, 0, stream>>>(src, dst, cursor, csr, N_EDGES);
    k_node_prep<<<(N_NODES + 255) / 256, 256, 0, stream>>>(x, deg, dinv, t, N_NODES);
    k_fused1  <<<((size_t)N_NODES * 64 + 255) / 256, 256, 0, stream>>>(
        rowptr, csr, t, dinv, W1, b1, W2, g, N_NODES);
    k_fused2  <<<((size_t)N_NODES * 64 + 255) / 256, 256, 0, stream>>>(
        rowptr, csr, g, dinv, b2, Wl, y, N_NODES);
    k_pool    <<<N_GRAPHS, 256, 0, stream>>>(y, batch, bl, (float*)d_out, N_NODES);
}

// Round 4
// 299.104 us; speedup vs baseline: 3.5238x; 1.4119x over previous
//
#include <hip/hip_runtime.h>

#define N_NODES  100000
#define N_EDGES  1600000
#define N_GRAPHS 256
#define NB       196     // buckets of 512 dst-nodes (100000/512 -> 196)
#define BSHIFT   9
#define EPB      6250    // edges per binning block (256 blocks * 6250 = 1.6M exactly)
#define EPT      25      // ceil(EPB/256)
#define CAP      10240   // LDS csr staging per bucket (mean 8192, ~22 sigma margin)

// ---- CSR build: two-level counting sort ---------------------------------

// A1: coarse bucket histogram (LDS-reduced, 196 global atomics per block)
__global__ void k_bucket_hist(const int* __restrict__ dst, int* __restrict__ bucketCount) {
    __shared__ int cnt[NB];
    int tid = threadIdx.x;
    for (int b = tid; b < NB; b += 256) cnt[b] = 0;
    __syncthreads();
    int base = blockIdx.x * EPB;
#pragma unroll
    for (int u = 0; u < EPT; ++u) {
        int o = u * 256 + tid;
        if (o < EPB) atomicAdd(&cnt[dst[base + o] >> BSHIFT], 1);
    }
    __syncthreads();
    for (int b = tid; b < NB; b += 256) if (cnt[b]) atomicAdd(&bucketCount[b], cnt[b]);
}

// A2: exclusive scan of the 196 bucket counts -> base + working cursor
__global__ void k_bucket_scan(const int* __restrict__ bucketCount,
                              int* __restrict__ bucketBase, int* __restrict__ bucketCursor) {
    __shared__ int sm[256];
    int tid = threadIdx.x;
    int v = (tid < NB) ? bucketCount[tid] : 0;
    sm[tid] = v; __syncthreads();
    for (int st = 1; st < 256; st <<= 1) {
        int t_ = (tid >= st) ? sm[tid - st] : 0;
        __syncthreads();
        sm[tid] += t_;
        __syncthreads();
    }
    if (tid < NB) { int ex = sm[tid] - v; bucketBase[tid] = ex; bucketCursor[tid] = ex; }
}

// A3: bin edges into ebin[] as int2(src,dst); per-(block,bucket) contiguous chunks
__global__ void k_bin(const int* __restrict__ src, const int* __restrict__ dst,
                      int* __restrict__ bucketCursor, int2* __restrict__ ebin) {
    __shared__ int cnt[NB], rnk[NB], base_[NB];
    int tid = threadIdx.x;
    for (int b = tid; b < NB; b += 256) { cnt[b] = 0; rnk[b] = 0; }
    __syncthreads();
    int base = blockIdx.x * EPB;
    int2 le[EPT];
#pragma unroll
    for (int u = 0; u < EPT; ++u) {
        int o = u * 256 + tid;
        if (o < EPB) {
            le[u].x = src[base + o];
            le[u].y = dst[base + o];
            atomicAdd(&cnt[le[u].y >> BSHIFT], 1);
        }
    }
    __syncthreads();
    for (int b = tid; b < NB; b += 256)
        base_[b] = cnt[b] ? atomicAdd(&bucketCursor[b], cnt[b]) : 0;
    __syncthreads();
#pragma unroll
    for (int u = 0; u < EPT; ++u) {
        int o = u * 256 + tid;
        if (o < EPB) {
            int b = le[u].y >> BSHIFT;
            int r = atomicAdd(&rnk[b], 1);
            ebin[base_[b] + r] = le[u];
        }
    }
}

// B1: per-bucket node degree via LDS hist (no global atomics); fused dinv/t prep
__global__ void k_deg_prep(const int2* __restrict__ ebin, const int* __restrict__ bucketBase,
                           const int* __restrict__ bucketCount, const float* __restrict__ x,
                           int* __restrict__ deg, float* __restrict__ dinv,
                           float* __restrict__ t, int nN) {
    __shared__ int hist[512];
    int tid = threadIdx.x, b = blockIdx.x;
    hist[tid] = 0; hist[tid + 256] = 0;
    __syncthreads();
    int s0 = bucketBase[b], n = bucketCount[b];
    for (int j = tid; j < n; j += 256) atomicAdd(&hist[ebin[s0 + j].y & 511], 1);
    __syncthreads();
#pragma unroll
    for (int u = 0; u < 2; ++u) {
        int node = b * 512 + u * 256 + tid;
        if (node < nN) {
            int dg = hist[u * 256 + tid];
            deg[node] = dg;
            float dv = rsqrtf((float)dg + 1.0f);
            dinv[node] = dv;
            t[node] = x[node] * dv;
        }
    }
}

// rowptr scan over deg (3-pass)
__global__ void k_scan1(const int* __restrict__ deg, int* __restrict__ bsum, int n) {
    __shared__ int sm[256];
    int base = blockIdx.x * 1024 + threadIdx.x * 4;
    int s = 0;
#pragma unroll
    for (int u = 0; u < 4; ++u) { int idx = base + u; if (idx < n) s += deg[idx]; }
    sm[threadIdx.x] = s; __syncthreads();
    for (int st = 128; st > 0; st >>= 1) {
        if (threadIdx.x < st) sm[threadIdx.x] += sm[threadIdx.x + st];
        __syncthreads();
    }
    if (threadIdx.x == 0) bsum[blockIdx.x] = sm[0];
}

__global__ void k_scan2(int* __restrict__ bsum, int nb) {
    __shared__ int sm[128];
    int v = ((int)threadIdx.x < nb) ? bsum[threadIdx.x] : 0;
    sm[threadIdx.x] = v; __syncthreads();
    for (int st = 1; st < 128; st <<= 1) {
        int t_ = ((int)threadIdx.x >= st) ? sm[threadIdx.x - st] : 0;
        __syncthreads();
        sm[threadIdx.x] += t_;
        __syncthreads();
    }
    if ((int)threadIdx.x < nb) bsum[threadIdx.x] = sm[threadIdx.x] - v;  // exclusive
}

__global__ void k_scan3(const int* __restrict__ deg, const int* __restrict__ bsum,
                        int* __restrict__ rowptr, int n) {
    __shared__ int sm[256];
    int base = blockIdx.x * 1024 + threadIdx.x * 4;
    int v[4]; int s = 0;
#pragma unroll
    for (int u = 0; u < 4; ++u) { int idx = base + u; v[u] = (idx < n) ? deg[idx] : 0; s += v[u]; }
    sm[threadIdx.x] = s; __syncthreads();
    for (int st = 1; st < 256; st <<= 1) {
        int t_ = ((int)threadIdx.x >= st) ? sm[threadIdx.x - st] : 0;
        __syncthreads();
        sm[threadIdx.x] += t_;
        __syncthreads();
    }
    int off = bsum[blockIdx.x] + sm[threadIdx.x] - s;
#pragma unroll
    for (int u = 0; u < 4; ++u) {
        int idx = base + u;
        if (idx < n) { rowptr[idx] = off; off += v[u]; }
    }
    if (blockIdx.x == 0 && threadIdx.x == 0) rowptr[n] = N_EDGES;
}

// B2: per-bucket csr fill, staged in LDS, dumped fully coalesced
__global__ void k_csr_fill2(const int2* __restrict__ ebin, const int* __restrict__ bucketBase,
                            const int* __restrict__ bucketCount, const int* __restrict__ rowptr,
                            int* __restrict__ csr, int nN) {
    __shared__ int loff[513];
    __shared__ int rnk[512];
    __shared__ int stage[CAP];
    int tid = threadIdx.x, b = blockIdx.x;
    int csrBase = rowptr[min(b * 512, nN)];
    for (int u = tid; u < 513; u += 256) loff[u] = rowptr[min(b * 512 + u, nN)] - csrBase;
    for (int u = tid; u < 512; u += 256) rnk[u] = 0;
    __syncthreads();
    int s0 = bucketBase[b], n = bucketCount[b];
    if (n <= CAP) {
        for (int j = tid; j < n; j += 256) {
            int2 e = ebin[s0 + j];
            int ld = e.y & 511;
            int r = atomicAdd(&rnk[ld], 1);
            stage[loff[ld] + r] = e.x;
        }
        __syncthreads();
        for (int j = tid; j < n; j += 256) csr[csrBase + j] = stage[j];
    } else {  // distribution-independent fallback (never expected)
        for (int j = tid; j < n; j += 256) {
            int2 e = ebin[s0 + j];
            int ld = e.y & 511;
            int r = atomicAdd(&rnk[ld], 1);
            csr[csrBase + loff[ld] + r] = e.x;
        }
    }
}

// ---- Node compute -------------------------------------------------------

// wave per node: agg1 gather + layer1 MLP + W2 projection -> g[i][k]
__global__ void k_fused1(const int* __restrict__ rowptr, const int* __restrict__ csr,
                         const float* __restrict__ t, const float* __restrict__ dinv,
                         const float* __restrict__ W1, const float* __restrict__ b1,
                         const float* __restrict__ W2, float* __restrict__ g, int nN) {
    __shared__ float sW1[32], sb1[32], sW2[32 * 64];
    int tid = threadIdx.x;
    if (tid < 32) { sW1[tid] = W1[tid]; sb1[tid] = b1[tid]; }
    for (int j = tid; j < 32 * 64; j += 256) sW2[j] = W2[j];
    __syncthreads();
    int i    = (blockIdx.x * 256 + tid) >> 6;
    int lane = tid & 63;
    if (i >= nN) return;
    int rs = rowptr[i], re = rowptr[i + 1];
    float a1 = 0.f;
    for (int j = rs + lane; j < re; j += 64) a1 += t[csr[j]];
#pragma unroll
    for (int st = 32; st > 0; st >>= 1) a1 += __shfl_xor(a1, st, 64);
    float dv = dinv[i];
    float a  = dv * (a1 + t[i]);
    float acc = 0.f;
#pragma unroll
    for (int j = 0; j < 32; ++j) {
        float h1 = fmaxf(fmaf(a, sW1[j], sb1[j]), 0.f);
        acc = fmaf(h1, sW2[j * 64 + lane], acc);
    }
    g[(size_t)i * 64 + lane] = acc * dv;
}

// wave per node, lane = channel: layer-2 gather + epilogue + y = h2 . Wl
__global__ void k_fused2(const int* __restrict__ rowptr, const int* __restrict__ csr,
                         const float* __restrict__ g, const float* __restrict__ dinv,
                         const float* __restrict__ b2, const float* __restrict__ Wl,
                         float* __restrict__ y, int nN) {
    int tid  = threadIdx.x;
    int i    = (blockIdx.x * 256 + tid) >> 6;
    int lane = tid & 63;
    if (i >= nN) return;
    int rs = rowptr[i], re = rowptr[i + 1];
    float acc0 = 0.f, acc1 = 0.f;
    int j = rs;
    for (; j + 1 < re; j += 2) {
        int s0 = csr[j], s1 = csr[j + 1];
        acc0 += g[(size_t)s0 * 64 + lane];
        acc1 += g[(size_t)s1 * 64 + lane];
    }
    if (j < re) acc0 += g[(size_t)csr[j] * 64 + lane];
    float acc = acc0 + acc1 + g[(size_t)i * 64 + lane];
    float h2 = fmaxf(fmaf(dinv[i], acc, b2[lane]), 0.f);
    float yv = h2 * Wl[lane];
#pragma unroll
    for (int st = 32; st > 0; st >>= 1) yv += __shfl_xor(yv, st, 64);
    if (lane == 0) y[i] = yv;
}

// one block per graph: binary-search sorted batch, reduce y
__global__ void k_pool(const float* __restrict__ y, const int* __restrict__ batch,
                       const float* __restrict__ bl, float* __restrict__ out, int nN) {
    int gid = blockIdx.x;
    int lo = 0, hi = nN;
    while (lo < hi) { int m = (lo + hi) >> 1; if (batch[m] < gid) lo = m + 1; else hi = m; }
    int start = lo;
    hi = nN;
    while (lo < hi) { int m = (lo + hi) >> 1; if (batch[m] < gid + 1) lo = m + 1; else hi = m; }
    int end = lo;

    float acc = 0.f;
    for (int i = start + threadIdx.x; i < end; i += blockDim.x) acc += y[i];
#pragma unroll
    for (int off = 32; off > 0; off >>= 1) acc += __shfl_down(acc, off, 64);
    __shared__ float ws_[4];
    int lane = threadIdx.x & 63, wv = threadIdx.x >> 6;
    if (lane == 0) ws_[wv] = acc;
    __syncthreads();
    if (threadIdx.x == 0) {
        float s = ws_[0] + ws_[1] + ws_[2] + ws_[3];
        out[gid] = s / fmaxf((float)(end - start), 1.0f) + bl[0];
    }
}

extern "C" void kernel_launch(void* const* d_in, const int* in_sizes, int n_in,
                              void* d_out, int out_size, void* d_ws, size_t ws_size,
                              hipStream_t stream) {
    const float* x   = (const float*)d_in[0];
    const int* eidx  = (const int*)d_in[1];
    const int* batch = (const int*)d_in[2];
    const float* W1  = (const float*)d_in[3];
    const float* b1  = (const float*)d_in[4];
    const float* W2  = (const float*)d_in[5];
    const float* b2  = (const float*)d_in[6];
    const float* Wl  = (const float*)d_in[7];
    const float* bl  = (const float*)d_in[8];
    const int* src = eidx;
    const int* dst = eidx + N_EDGES;

    const int SCAN_NB = (N_NODES + 1023) / 1024;   // 98

    char* ws = (char*)d_ws;
    size_t off = 0;
    auto alloc = [&](size_t elems) { void* p = ws + off; off += elems * 4; return p; };
    int2*  ebin    = (int2*)alloc((size_t)N_EDGES * 2);   // first: 8B-aligned
    int*   csr     = (int*)alloc(N_EDGES);
    int*   rowptr  = (int*)alloc(N_NODES + 1);
    int*   deg     = (int*)alloc(N_NODES);
    int*   bcount  = (int*)alloc(256);                    // must start at 0
    int*   bbase   = (int*)alloc(256);
    int*   bcursor = (int*)alloc(256);
    int*   bsum    = (int*)alloc(128);
    float* dinv    = (float*)alloc(N_NODES);
    float* t       = (float*)alloc(N_NODES);
    float* g       = (float*)alloc((size_t)N_NODES * 64);
    float* y       = (float*)alloc(N_NODES);

    hipMemsetAsync(bcount, 0, 256 * sizeof(int), stream);

    k_bucket_hist<<<256, 256, 0, stream>>>(dst, bcount);
    k_bucket_scan<<<1, 256, 0, stream>>>(bcount, bbase, bcursor);
    k_bin        <<<256, 256, 0, stream>>>(src, dst, bcursor, ebin);
    k_deg_prep   <<<NB, 256, 0, stream>>>(ebin, bbase, bcount, x, deg, dinv, t, N_NODES);
    k_scan1      <<<SCAN_NB, 256, 0, stream>>>(deg, bsum, N_NODES);
    k_scan2      <<<1, 128, 0, stream>>>(bsum, SCAN_NB);
    k_scan3      <<<SCAN_NB, 256, 0, stream>>>(deg, bsum, rowptr, N_NODES);
    k_csr_fill2  <<<NB, 256, 0, stream>>>(ebin, bbase, bcount, rowptr, csr, N_NODES);
    k_fused1     <<<((size_t)N_NODES * 64 + 255) / 256, 256, 0, stream>>>(
        rowptr, csr, t, dinv, W1, b1, W2, g, N_NODES);
    k_fused2     <<<((size_t)N_NODES * 64 + 255) / 256, 256, 0, stream>>>(
        rowptr, csr, g, dinv, b2, Wl, y, N_NODES);
    k_pool       <<<N_GRAPHS, 256, 0, stream>>>(y, batch, bl, (float*)d_out, N_NODES);
}